// Round 10
// baseline (2150.916 us; speedup 1.0000x reference)
//
#include <hip/hip_runtime.h>
#include <cstdint>
#include <cstddef>

// SNN forward, fp32-faithful (bitwise-identical accumulation order):
//  - strict __fmul_rn/__fadd_rn LIF, ascending-k __fmaf_rn reductions, bias AFTER
//  - conv2 k-order (ic,kr,kc); x10 after bias; spike (vd-1)>0
// Round 16: REVERT to the unfused R2 structure (fusion family never beat 1589 over
// 3 refinement rounds; decision rule from R15). Kept orthogonal wins:
//  - 3 barriers/step: merged scan2(ts)|scan3(ts-1) on waves 0|1; out(ts-1) runs on
//    tids 500-509 concurrently with fc(ts) in stage S; no trailing barrier.
//  - fc: byte-offset list2i + readfirstlane SGPR row base; 32-wide ping-pong,
//    guard-free full batches; tail loads unguarded via 32-entry zero pad.
//  - L1 LIF state BACK in registers (R2 proved it fits 128 VGPR, no spill).
// New: w2 -> LDS ONCE at init (R7's regression was per-step re-staging, not LDS
//  residency). Kills 500 global loads/thread/step (8x-redundant weight refetch,
//  ~800KB/step/block L2 traffic). Layout [50][20][28], oc stride 564 floats:
//  ic-rows 16B-aligned (ds_read_b128-able) and 8 oc-groups/wave -> 8 distinct
//  banks (564*4 % 128 = 80B -> bank step 20, coprime-ish with 32). LDS ~155KB.

#define TSTEPS 64
#define NB 256

#define RFL(v) __builtin_amdgcn_readfirstlane(v)

__global__ __launch_bounds__(256)
void transpose_wfc(const float* __restrict__ wfc, float* __restrict__ wfcT) {
    int idx = blockIdx.x * 256 + threadIdx.x;     // [500,800] -> [800,500]
    if (idx < 500 * 800) {
        int o = idx / 800, j = idx % 800;
        wfcT[j * 500 + o] = wfc[idx];
    }
}

__global__ __launch_bounds__(512)
void snn_forward(const float* __restrict__ x,      // [64,256,1,28,28]
                 const float* __restrict__ w1,     // [20,1,5,5]
                 const float* __restrict__ b1,     // [20]
                 const float* __restrict__ w2,     // [50,20,5,5]
                 const float* __restrict__ b2,     // [50]
                 const float* __restrict__ fcw,    // wfcT [800,500] (sj=500,so=1) or wfc [500,800]
                 long fc_sj, long fc_so,
                 const float* __restrict__ bfc,    // [500]
                 const float* __restrict__ wout,   // [10,500]
                 float* __restrict__ out)          // [64,256,10]
{
    const float CM = 0.1f;
    const float CS = 0.8f;

    const int b   = blockIdx.x;
    const int tid = threadIdx.x;

    // ---- LDS (~155 KB) ----
    __shared__ float xs[2][28 * 36];                 // double-buffered input tile (8 KB)
    __shared__ float p1[20 * 12 * 12];               // pooled L1 spikes (11.5 KB)
    __shared__ float w1L[500];                       // conv1 weights (2 KB)
    __shared__ float woutL[5000];                    // wout [10,500] (20 KB)
    __shared__ float w2L[50 * 564];                  // conv2 weights [oc][ic][28], oc stride 564 (112.8 KB)
    __shared__ unsigned int bm2[25];                 // pooled-L2 bitmap (800 bits)
    __shared__ unsigned int bm3[16];                 // L3 bitmap (500 bits)
    __shared__ int list2i[848];                      // active fc rows as BYTE offsets (asc) + pad
    __shared__ unsigned short list3s[512];           // active L3 indices (asc)
    __shared__ int nn2s, nn3s;

    // ---- one-time init ----
    if (tid < 500) w1L[tid] = w1[tid];
    if (tid < 25)  bm2[tid] = 0u;
    if (tid == 0)  { nn2s = 0; nn3s = 0; }
    for (int i = tid; i < 5000; i += 512) woutL[i] = wout[i];
    for (int i = tid; i < 25000; i += 512) {
        const int oc = i / 500, r = i - oc * 500;
        const int ic = r / 25,  k = r - ic * 25;
        w2L[oc * 564 + ic * 28 + k] = w2[i];
    }

    // staging index map (constant per thread)
    const int sr0 = tid / 28,         sc0_ = tid - sr0 * 28;           // elem tid
    const int has2 = (tid + 512) < 784;
    const int sr1 = (tid + 512) / 28, sc1_ = (tid + 512) - sr1 * 28;   // elem tid+512

    // prologue: stage ts=0
    {
        const float* xp = x + ((size_t)b) * 784;     // ts=0
        xs[0][sr0 * 36 + sc0_] = xp[tid];
        if (has2) xs[0][sr1 * 36 + sc1_] = xp[tid + 512];
    }

    // ---- layer-1 mapping: 480 threads = 20 ch x 12 pool-rows x 2 col-halves ----
    const int l1  = (tid < 480);
    const int c   = tid / 24;
    const int sub = tid % 24;
    const int pr  = sub >> 1;
    const int chh = sub & 1;
    const int r0  = pr * 2;
    const int c0  = chh * 12;

    float v0a[12], v0b[12], i0a[12], i0b[12];        // L1 LIF state (registers, 48)
    #pragma unroll
    for (int j = 0; j < 12; ++j) { v0a[j] = 0.f; v0b[j] = 0.f; i0a[j] = 0.f; i0b[j] = 0.f; }

    // ---- layer-2 mapping: 400 threads = 50 oc x 8 out-rows; 8 cols each ----
    const int l2  = (tid < 400);
    const int oc2 = tid >> 3;
    const int y2  = tid & 7;
    const float bias2 = l2 ? b2[oc2] : 0.f;
    const float bias1 = l1 ? b1[c] : 0.f;
    const float* w2Lb = w2L + oc2 * 564;             // this oc's LDS weight base

    float vL2[8], iL2[8];                            // L2 LIF state (registers)
    #pragma unroll
    for (int q = 0; q < 8; ++q) { vL2[q] = 0.f; iL2[q] = 0.f; }

    float vL3 = 0.f, iL3 = 0.f;                      // L3 LIF state (registers)
    const float bfc_r = (tid < 500) ? bfc[tid] : 0.f;

    float vO = 0.f, iO = 0.f;                        // output LI state (registers)

    // fc addressing (scalar row base via readfirstlane'd list2i entries)
    const char* __restrict__ fcb = (const char*)fcw;
    const int coff  = (int)((long)tid * fc_so) * 4;  // per-thread column byte offset
    const int coffE = (tid < 500) ? coff : 0;        // OOB guard for lanes >= 500

// fc batch helpers: 32-wide. Loads unguarded (list zero-padded). Full batches
// consume with PLAIN fma -- bitwise identical since every element is real.
#define FC_LOAD32(F_, kk_) do { _Pragma("unroll") \
    for (int q_ = 0; q_ < 32; ++q_) { \
        const int o_ = RFL(list2i[(kk_) + q_]); \
        F_[q_] = *(const float*)(fcb + (size_t)(unsigned)(o_ + coffE)); } } while (0)
#define FC_FMA32(fca_, F_) do { _Pragma("unroll") \
    for (int q_ = 0; q_ < 32; ++q_) (fca_) = __fmaf_rn(1.0f, F_[q_], (fca_)); } while (0)

    __syncthreads();   // init (incl. w2L) + xs[0] ready

    for (int ts = 0; ts < TSTEPS; ++ts) {
        const int cur = ts & 1, nxt = cur ^ 1;

        // ===== stage P: conv1(ts) + x prefetch + conv2 ic=0 weight prefetch (LDS) =====
        float xpre0 = 0.f, xpre1 = 0.f;
        if (ts + 1 < TSTEPS) {
            const float* xpn = x + ((size_t)(ts + 1) * NB + b) * 784;
            xpre0 = xpn[tid];
            if (has2) xpre1 = xpn[tid + 512];
        }
        float wcur[25];
        if (l2) {
            #pragma unroll
            for (int q = 0; q < 25; ++q) wcur[q] = w2Lb[q];   // ic=0 row (LDS, aligned)
        }

        if (l1) {
            float acc0[12], acc1[12];
            #pragma unroll
            for (int j = 0; j < 12; ++j) { acc0[j] = 0.f; acc1[j] = 0.f; }
            float wc[5], wp[5];
            #pragma unroll
            for (int ir = 0; ir < 6; ++ir) {
                float xr[16];
                const float4* rp = (const float4*)(xs[cur] + (r0 + ir) * 36 + c0);
                #pragma unroll
                for (int q = 0; q < 4; ++q) {
                    float4 f = rp[q];
                    xr[4*q+0] = f.x; xr[4*q+1] = f.y; xr[4*q+2] = f.z; xr[4*q+3] = f.w;
                }
                if (ir < 5) {                      // rolling weight window
                    #pragma unroll
                    for (int k = 0; k < 5; ++k) wc[k] = w1L[c * 25 + ir * 5 + k];
                    #pragma unroll
                    for (int kc = 0; kc < 5; ++kc) {
                        const float w = wc[kc];
                        #pragma unroll
                        for (int j = 0; j < 12; ++j)
                            acc0[j] = __fmaf_rn(w, xr[j + kc], acc0[j]);
                    }
                }
                if (ir >= 1) {                     // out row r0+1, kr = ir-1 -> wp
                    #pragma unroll
                    for (int kc = 0; kc < 5; ++kc) {
                        const float w = wp[kc];
                        #pragma unroll
                        for (int j = 0; j < 12; ++j)
                            acc1[j] = __fmaf_rn(w, xr[j + kc], acc1[j]);
                    }
                }
                #pragma unroll
                for (int k = 0; k < 5; ++k) wp[k] = wc[k];
            }
            unsigned int zb0 = 0, zb1 = 0;
            #pragma unroll
            for (int j = 0; j < 12; ++j) {
                const float inp = __fadd_rn(acc0[j], bias1);
                const float vd  = __fadd_rn(v0a[j], __fmul_rn(CM, __fsub_rn(i0a[j], v0a[j])));
                const float id  = __fmul_rn(i0a[j], CS);
                const int z = (__fsub_rn(vd, 1.0f) > 0.0f);
                v0a[j] = z ? 0.f : vd;
                i0a[j] = __fadd_rn(id, inp);
                zb0 |= (unsigned)z << j;
            }
            #pragma unroll
            for (int j = 0; j < 12; ++j) {
                const float inp = __fadd_rn(acc1[j], bias1);
                const float vd  = __fadd_rn(v0b[j], __fmul_rn(CM, __fsub_rn(i0b[j], v0b[j])));
                const float id  = __fmul_rn(i0b[j], CS);
                const int z = (__fsub_rn(vd, 1.0f) > 0.0f);
                v0b[j] = z ? 0.f : vd;
                i0b[j] = __fadd_rn(id, inp);
                zb1 |= (unsigned)z << j;
            }
            const unsigned int zp = zb0 | zb1;
            #pragma unroll
            for (int jj = 0; jj < 6; ++jj)
                p1[(c * 12 + pr) * 12 + chh * 6 + jj] = ((zp >> (2 * jj)) & 3u) ? 1.0f : 0.0f;
        }
        if (ts + 1 < TSTEPS) {
            xs[nxt][sr0 * 36 + sc0_] = xpre0;
            if (has2) xs[nxt][sr1 * 36 + sc1_] = xpre1;
        }
        __syncthreads();   // (B1) p1(ts) ready

        // ===== stage Q: conv2(ts) DENSE (weights from LDS, reg double-buffer) + LIF2 =====
        if (l2) {
            float acc[8];
            #pragma unroll
            for (int xx = 0; xx < 8; ++xx) acc[xx] = 0.f;
            float4 ra, rb, rc;
            {
                const float4* pp = (const float4*)(p1 + y2 * 12);   // (ic=0,kr=0)
                ra = pp[0]; rb = pp[1]; rc = pp[2];
            }
            float wnxt[25];

            for (int ic = 0; ic < 20; ++ic) {
                if (ic + 1 < 20) {                   // next-ic weights early (LDS, 1 ic ahead)
                    const float* wn = w2Lb + (ic + 1) * 28;
                    #pragma unroll
                    for (int q = 0; q < 25; ++q) wnxt[q] = wn[q];
                }
                #pragma unroll
                for (int kr = 0; kr < 5; ++kr) {
                    float4 na, nb, nc;
                    const bool last = (ic == 19) && (kr == 4);
                    if (!last) {                     // next row load
                        const int nic = (kr == 4) ? ic + 1 : ic;
                        const int nkr = (kr == 4) ? 0 : kr + 1;
                        const float4* pp = (const float4*)(p1 + (nic * 12 + y2 + nkr) * 12);
                        na = pp[0]; nb = pp[1]; nc = pp[2];
                    }
                    const float pv[12] = { ra.x,ra.y,ra.z,ra.w, rb.x,rb.y,rb.z,rb.w, rc.x,rc.y,rc.z,rc.w };
                    const float w0  = wcur[kr*5+0], w1_ = wcur[kr*5+1], w2w = wcur[kr*5+2];
                    const float w3_ = wcur[kr*5+3], w4_ = wcur[kr*5+4];
                    #pragma unroll
                    for (int xx = 0; xx < 8; ++xx) acc[xx] = __fmaf_rn(w0, pv[xx],     acc[xx]);
                    #pragma unroll
                    for (int xx = 0; xx < 8; ++xx) acc[xx] = __fmaf_rn(w1_, pv[xx + 1], acc[xx]);
                    #pragma unroll
                    for (int xx = 0; xx < 8; ++xx) acc[xx] = __fmaf_rn(w2w, pv[xx + 2], acc[xx]);
                    #pragma unroll
                    for (int xx = 0; xx < 8; ++xx) acc[xx] = __fmaf_rn(w3_, pv[xx + 3], acc[xx]);
                    #pragma unroll
                    for (int xx = 0; xx < 8; ++xx) acc[xx] = __fmaf_rn(w4_, pv[xx + 4], acc[xx]);
                    if (!last) { ra = na; rb = nb; rc = nc; }
                }
                if (ic + 1 < 20) {
                    #pragma unroll
                    for (int q = 0; q < 25; ++q) wcur[q] = wnxt[q];
                }
            }

            unsigned int pb = 0;                     // pooled bits for bm2
            const unsigned int bitbase = (unsigned)((oc2 & 1) * 16 + (y2 >> 1) * 4);
            #pragma unroll
            for (int xx = 0; xx < 8; ++xx) {
                const float inp = __fmul_rn(10.0f, __fadd_rn(acc[xx], bias2));
                const float vd  = __fadd_rn(vL2[xx], __fmul_rn(CM, __fsub_rn(iL2[xx], vL2[xx])));
                const float id  = __fmul_rn(iL2[xx], CS);
                const int z = (__fsub_rn(vd, 1.0f) > 0.0f);
                vL2[xx] = z ? 0.f : vd;
                iL2[xx] = __fadd_rn(id, inp);
                if (z) pb |= 1u << (bitbase + (xx >> 1));
            }
            if (pb) atomicOr(&bm2[oc2 >> 1], pb);
        }
        __syncthreads();   // (B2) bm2(ts) complete [bm3(ts-1) complete since S(ts-1)]

        // ===== stage R: scan2(ts) on wave0 | scan3(ts-1) on wave1 =====
        if (tid < 64) {
            unsigned int bits = (tid < 25) ? bm2[tid] : 0u;
            if (tid < 25) bm2[tid] = 0u;             // consumed; next writer conv2(ts+1)
            int cnt = __popc(bits);
            int inc = cnt;
            #pragma unroll
            for (int d = 1; d < 32; d <<= 1) {
                int n = __shfl_up(inc, d);
                if (tid >= d) inc += n;
            }
            int off = inc - cnt;                     // exclusive prefix
            if (tid == 24) nn2s = inc;
            const int tot = __shfl(inc, 24);         // total, all lanes
            const int jstride = (int)fc_sj * 4;
            const int base = tid * 32;
            while (bits) {
                const int bb = __builtin_ctz(bits);
                bits &= bits - 1;
                list2i[off++] = (base + bb) * jstride;
            }
            if (tid >= 32) list2i[tot + (tid - 32)] = 0;   // 32-entry zero pad
        } else if (tid < 128 && ts > 0) {
            const int t3 = tid - 64;
            unsigned int bits = (t3 < 16) ? bm3[t3] : 0u;
            int cnt = __popc(bits);
            int inc = cnt;
            #pragma unroll
            for (int d = 1; d < 16; d <<= 1) {
                int n = __shfl_up(inc, d);
                if (t3 >= d) inc += n;
            }
            int off = inc - cnt;
            if (t3 == 15) nn3s = inc;
            while (bits) {
                const int bb = __builtin_ctz(bits);
                bits &= bits - 1;
                list3s[off++] = (unsigned short)(t3 * 32 + bb);
            }
        }
        __syncthreads();   // (B3) list2i(ts), list3s(ts-1) ready

        // ===== stage S: fc(ts)+LIF3 on tids 0-499 | out(ts-1) on tids 500-509 =====
        if (tid < 500) {
            const int nn2 = nn2s;
            float fca = 0.f;
            int k = 0;
            const int nb32 = nn2 >> 5;               // full 32-batches
            if (nb32 >= 1) {                          // ping-pong, guard-free
                float A[32], B[32];
                FC_LOAD32(A, 0);
                int j = 1;
                for (; j + 1 < nb32; j += 2) {
                    FC_LOAD32(B, j * 32);
                    FC_FMA32(fca, A);
                    FC_LOAD32(A, (j + 1) * 32);
                    FC_FMA32(fca, B);
                }
                if (j < nb32) {
                    FC_LOAD32(B, j * 32);
                    FC_FMA32(fca, A);
                    FC_FMA32(fca, B);
                } else {
                    FC_FMA32(fca, A);
                }
                k = nb32 * 32;
            }
            {                                         // tail <=31: unguarded loads (pad), guarded fma
                const int rem = nn2 - k;
                float T[31];
                #pragma unroll
                for (int q = 0; q < 31; ++q) {
                    const int o_ = RFL(list2i[k + q]);
                    T[q] = *(const float*)(fcb + (size_t)(unsigned)(o_ + coffE));
                }
                #pragma unroll
                for (int q = 0; q < 31; ++q)
                    if (q < rem) fca = __fmaf_rn(1.0f, T[q], fca);
            }
            const float inp = __fadd_rn(fca, bfc_r);
            const float vd  = __fadd_rn(vL3, __fmul_rn(CM, __fsub_rn(iL3, vL3)));
            const float id  = __fmul_rn(iL3, CS);
            const int z = (__fsub_rn(vd, 1.0f) > 0.0f);
            vL3 = z ? 0.f : vd;
            iL3 = __fadd_rn(id, inp);
            const unsigned long long m = __ballot(z); // full-word overwrite, no atomics
            if ((tid & 63) == 0) {
                bm3[(tid >> 5)]     = (unsigned int)m;
                bm3[(tid >> 5) + 1] = (unsigned int)(m >> 32);
            }
        } else if (tid < 510 && ts > 0) {
            const int otid = tid - 500;
            const float* wrow_ = woutL + otid * 500;
            const int nn3 = nn3s;
            float acc = 0.f;
            int k = 0;
            const int kfull = nn3 & ~7;
            if (kfull > 0) {                          // 8-wide, 2-deep pipeline (LDS)
                float a[8];
                #pragma unroll
                for (int q = 0; q < 8; ++q) a[q] = wrow_[list3s[q]];
                for (k = 8; k < kfull; k += 8) {
                    float bv[8];
                    #pragma unroll
                    for (int q = 0; q < 8; ++q) bv[q] = wrow_[list3s[k + q]];
                    #pragma unroll
                    for (int q = 0; q < 8; ++q) acc = __fmaf_rn(1.0f, a[q], acc);
                    #pragma unroll
                    for (int q = 0; q < 8; ++q) a[q] = bv[q];
                }
                #pragma unroll
                for (int q = 0; q < 8; ++q) acc = __fmaf_rn(1.0f, a[q], acc);
                k = kfull;
            }
            {
                const int rem3 = nn3 - k;
                float t[7];
                #pragma unroll
                for (int q = 0; q < 7; ++q) t[q] = (q < rem3) ? wrow_[list3s[k + q]] : 0.f;
                #pragma unroll
                for (int q = 0; q < 7; ++q) if (q < rem3) acc = __fmaf_rn(1.0f, t[q], acc);
            }
            const float vn = __fadd_rn(vO, __fmul_rn(CM, __fsub_rn(iO, vO)));
            iO = __fadd_rn(__fmul_rn(iO, CS), acc);
            vO = vn;
            out[((size_t)(ts - 1) * NB + b) * 10 + otid] = vn;
        }
        // no trailing barrier: bm3(ts)/list consumers re-synchronize via B2/B3(ts+1);
        // P(ts+1) touches only xs/p1/x, disjoint from S's data.
    }

    // ===== tail: scan3(63) + out(63) =====
    __syncthreads();
    if (tid < 64) {
        unsigned int bits = (tid < 16) ? bm3[tid] : 0u;
        int cnt = __popc(bits);
        int inc = cnt;
        #pragma unroll
        for (int d = 1; d < 16; d <<= 1) {
            int n = __shfl_up(inc, d);
            if (tid >= d) inc += n;
        }
        int off = inc - cnt;
        if (tid == 15) nn3s = inc;
        while (bits) {
            const int bb = __builtin_ctz(bits);
            bits &= bits - 1;
            list3s[off++] = (unsigned short)(tid * 32 + bb);
        }
    }
    __syncthreads();
    {
        const int otid = tid - 500;
        if (otid >= 0 && otid < 10) {
            const float* wrow_ = woutL + otid * 500;
            const int nn3 = nn3s;
            float acc = 0.f;
            int k = 0;
            const int kfull = nn3 & ~7;
            if (kfull > 0) {
                float a[8];
                #pragma unroll
                for (int q = 0; q < 8; ++q) a[q] = wrow_[list3s[q]];
                for (k = 8; k < kfull; k += 8) {
                    float bv[8];
                    #pragma unroll
                    for (int q = 0; q < 8; ++q) bv[q] = wrow_[list3s[k + q]];
                    #pragma unroll
                    for (int q = 0; q < 8; ++q) acc = __fmaf_rn(1.0f, a[q], acc);
                    #pragma unroll
                    for (int q = 0; q < 8; ++q) a[q] = bv[q];
                }
                #pragma unroll
                for (int q = 0; q < 8; ++q) acc = __fmaf_rn(1.0f, a[q], acc);
                k = kfull;
            }
            {
                const int rem3 = nn3 - k;
                float t[7];
                #pragma unroll
                for (int q = 0; q < 7; ++q) t[q] = (q < rem3) ? wrow_[list3s[k + q]] : 0.f;
                #pragma unroll
                for (int q = 0; q < 7; ++q) if (q < rem3) acc = __fmaf_rn(1.0f, t[q], acc);
            }
            const float vn = __fadd_rn(vO, __fmul_rn(CM, __fsub_rn(iO, vO)));
            iO = __fadd_rn(__fmul_rn(iO, CS), acc);
            vO = vn;
            out[((size_t)(TSTEPS - 1) * NB + b) * 10 + otid] = vn;
        }
    }
}

extern "C" void kernel_launch(void* const* d_in, const int* in_sizes, int n_in,
                              void* d_out, int out_size, void* d_ws, size_t ws_size,
                              hipStream_t stream)
{
    const float* x    = (const float*)d_in[0];
    const float* w1   = (const float*)d_in[1];
    const float* b1   = (const float*)d_in[2];
    const float* w2   = (const float*)d_in[3];
    const float* b2   = (const float*)d_in[4];
    const float* wfc  = (const float*)d_in[5];
    const float* bfc  = (const float*)d_in[6];
    const float* wout = (const float*)d_in[7];
    float* out = (float*)d_out;

    const float* fcptr = wfc;
    long sj = 1, so = 800;
    if (ws_size >= (size_t)500 * 800 * sizeof(float)) {
        float* wfcT = (float*)d_ws;
        transpose_wfc<<<(500 * 800 + 255) / 256, 256, 0, stream>>>(wfc, wfcT);
        fcptr = wfcT; sj = 500; so = 1;
    }

    snn_forward<<<NB, 512, 0, stream>>>(x, w1, b1, w2, b2, fcptr, sj, so, bfc, wout, out);
}

// Round 11
// 1662.580 us; speedup vs baseline: 1.2937x; 1.2937x over previous
//
#include <hip/hip_runtime.h>
#include <cstdint>
#include <cstddef>

// SNN forward, fp32-faithful (bitwise-identical accumulation order):
//  - strict __fmul_rn/__fadd_rn LIF, ascending-k __fmaf_rn reductions, bias AFTER
//  - conv2 k-order (ic,kr,kc); x10 after bias; spike (vd-1)>0
// Round 17 delta (single revert vs round 16): REMOVE w2L LDS weight cache; w2 back
// to R2-style global register double-buffer (wcur/wnxt, 1 ic ahead). R10 spilled
// (908 MB scratch writes) -- this kernel sits exactly at the immovable 128-VGPR
// boundary and w2L's longer wcur liveness pushed it over. This round isolates the
// 3-barrier merge on top of the proven R2 register shape:
//  - 3 barriers/step: P(conv1) |B1| Q(conv2) |B2| R(scan2|scan3(ts-1)) |B3|
//    S(fc+LIF3 on tids 0-499 || out(ts-1) on tids 500-509), no trailing barrier.
//  - fc: byte-offset list2i + readfirstlane SGPR row base; 32-wide ping-pong,
//    guard-free full batches; tail loads unguarded via 32-entry zero pad.
//  - L1 LIF state in registers (R2-proven fit).

#define TSTEPS 64
#define NB 256

#define RFL(v) __builtin_amdgcn_readfirstlane(v)

__global__ __launch_bounds__(256)
void transpose_wfc(const float* __restrict__ wfc, float* __restrict__ wfcT) {
    int idx = blockIdx.x * 256 + threadIdx.x;     // [500,800] -> [800,500]
    if (idx < 500 * 800) {
        int o = idx / 800, j = idx % 800;
        wfcT[j * 500 + o] = wfc[idx];
    }
}

__global__ __launch_bounds__(512)
void snn_forward(const float* __restrict__ x,      // [64,256,1,28,28]
                 const float* __restrict__ w1,     // [20,1,5,5]
                 const float* __restrict__ b1,     // [20]
                 const float* __restrict__ w2,     // [50,20,5,5]
                 const float* __restrict__ b2,     // [50]
                 const float* __restrict__ fcw,    // wfcT [800,500] (sj=500,so=1) or wfc [500,800]
                 long fc_sj, long fc_so,
                 const float* __restrict__ bfc,    // [500]
                 const float* __restrict__ wout,   // [10,500]
                 float* __restrict__ out)          // [64,256,10]
{
    const float CM = 0.1f;
    const float CS = 0.8f;

    const int b   = blockIdx.x;
    const int tid = threadIdx.x;

    // ---- LDS (~47 KB) ----
    __shared__ float xs[2][28 * 36];                 // double-buffered input tile (8 KB)
    __shared__ float p1[20 * 12 * 12];               // pooled L1 spikes (11.5 KB)
    __shared__ float w1L[500];                       // conv1 weights (2 KB)
    __shared__ float woutL[5000];                    // wout [10,500] (20 KB)
    __shared__ unsigned int bm2[25];                 // pooled-L2 bitmap (800 bits)
    __shared__ unsigned int bm3[16];                 // L3 bitmap (500 bits)
    __shared__ int list2i[848];                      // active fc rows as BYTE offsets (asc) + pad
    __shared__ unsigned short list3s[512];           // active L3 indices (asc)
    __shared__ int nn2s, nn3s;

    // ---- one-time init ----
    if (tid < 500) w1L[tid] = w1[tid];
    if (tid < 25)  bm2[tid] = 0u;
    if (tid == 0)  { nn2s = 0; nn3s = 0; }
    for (int i = tid; i < 5000; i += 512) woutL[i] = wout[i];

    // staging index map (constant per thread)
    const int sr0 = tid / 28,         sc0_ = tid - sr0 * 28;           // elem tid
    const int has2 = (tid + 512) < 784;
    const int sr1 = (tid + 512) / 28, sc1_ = (tid + 512) - sr1 * 28;   // elem tid+512

    // prologue: stage ts=0
    {
        const float* xp = x + ((size_t)b) * 784;     // ts=0
        xs[0][sr0 * 36 + sc0_] = xp[tid];
        if (has2) xs[0][sr1 * 36 + sc1_] = xp[tid + 512];
    }

    // ---- layer-1 mapping: 480 threads = 20 ch x 12 pool-rows x 2 col-halves ----
    const int l1  = (tid < 480);
    const int c   = tid / 24;
    const int sub = tid % 24;
    const int pr  = sub >> 1;
    const int chh = sub & 1;
    const int r0  = pr * 2;
    const int c0  = chh * 12;

    float v0a[12], v0b[12], i0a[12], i0b[12];        // L1 LIF state (registers, 48)
    #pragma unroll
    for (int j = 0; j < 12; ++j) { v0a[j] = 0.f; v0b[j] = 0.f; i0a[j] = 0.f; i0b[j] = 0.f; }

    // ---- layer-2 mapping: 400 threads = 50 oc x 8 out-rows; 8 cols each ----
    const int l2  = (tid < 400);
    const int oc2 = tid >> 3;
    const int y2  = tid & 7;
    const float bias2 = l2 ? b2[oc2] : 0.f;
    const float bias1 = l1 ? b1[c] : 0.f;
    const float* w2base = w2 + (size_t)oc2 * 500;    // [20][25] for this oc (global)

    float vL2[8], iL2[8];                            // L2 LIF state (registers)
    #pragma unroll
    for (int q = 0; q < 8; ++q) { vL2[q] = 0.f; iL2[q] = 0.f; }

    float vL3 = 0.f, iL3 = 0.f;                      // L3 LIF state (registers)
    const float bfc_r = (tid < 500) ? bfc[tid] : 0.f;

    float vO = 0.f, iO = 0.f;                        // output LI state (registers)

    // fc addressing (scalar row base via readfirstlane'd list2i entries)
    const char* __restrict__ fcb = (const char*)fcw;
    const int coff  = (int)((long)tid * fc_so) * 4;  // per-thread column byte offset
    const int coffE = (tid < 500) ? coff : 0;        // OOB guard for lanes >= 500

// fc batch helpers: 32-wide. Loads unguarded (list zero-padded). Full batches
// consume with PLAIN fma -- bitwise identical since every element is real.
#define FC_LOAD32(F_, kk_) do { _Pragma("unroll") \
    for (int q_ = 0; q_ < 32; ++q_) { \
        const int o_ = RFL(list2i[(kk_) + q_]); \
        F_[q_] = *(const float*)(fcb + (size_t)(unsigned)(o_ + coffE)); } } while (0)
#define FC_FMA32(fca_, F_) do { _Pragma("unroll") \
    for (int q_ = 0; q_ < 32; ++q_) (fca_) = __fmaf_rn(1.0f, F_[q_], (fca_)); } while (0)

    __syncthreads();   // init + xs[0] ready

    for (int ts = 0; ts < TSTEPS; ++ts) {
        const int cur = ts & 1, nxt = cur ^ 1;

        // ===== stage P: conv1(ts) + x prefetch + conv2 ic=0 weight prefetch (global) =====
        float xpre0 = 0.f, xpre1 = 0.f;
        if (ts + 1 < TSTEPS) {
            const float* xpn = x + ((size_t)(ts + 1) * NB + b) * 784;
            xpre0 = xpn[tid];
            if (has2) xpre1 = xpn[tid + 512];
        }
        float wcur[25];
        if (l2) {
            #pragma unroll
            for (int q = 0; q < 25; ++q) wcur[q] = w2base[q];
        }

        if (l1) {
            float acc0[12], acc1[12];
            #pragma unroll
            for (int j = 0; j < 12; ++j) { acc0[j] = 0.f; acc1[j] = 0.f; }
            float wc[5], wp[5];
            #pragma unroll
            for (int ir = 0; ir < 6; ++ir) {
                float xr[16];
                const float4* rp = (const float4*)(xs[cur] + (r0 + ir) * 36 + c0);
                #pragma unroll
                for (int q = 0; q < 4; ++q) {
                    float4 f = rp[q];
                    xr[4*q+0] = f.x; xr[4*q+1] = f.y; xr[4*q+2] = f.z; xr[4*q+3] = f.w;
                }
                if (ir < 5) {                      // rolling weight window
                    #pragma unroll
                    for (int k = 0; k < 5; ++k) wc[k] = w1L[c * 25 + ir * 5 + k];
                    #pragma unroll
                    for (int kc = 0; kc < 5; ++kc) {
                        const float w = wc[kc];
                        #pragma unroll
                        for (int j = 0; j < 12; ++j)
                            acc0[j] = __fmaf_rn(w, xr[j + kc], acc0[j]);
                    }
                }
                if (ir >= 1) {                     // out row r0+1, kr = ir-1 -> wp
                    #pragma unroll
                    for (int kc = 0; kc < 5; ++kc) {
                        const float w = wp[kc];
                        #pragma unroll
                        for (int j = 0; j < 12; ++j)
                            acc1[j] = __fmaf_rn(w, xr[j + kc], acc1[j]);
                    }
                }
                #pragma unroll
                for (int k = 0; k < 5; ++k) wp[k] = wc[k];
            }
            unsigned int zb0 = 0, zb1 = 0;
            #pragma unroll
            for (int j = 0; j < 12; ++j) {
                const float inp = __fadd_rn(acc0[j], bias1);
                const float vd  = __fadd_rn(v0a[j], __fmul_rn(CM, __fsub_rn(i0a[j], v0a[j])));
                const float id  = __fmul_rn(i0a[j], CS);
                const int z = (__fsub_rn(vd, 1.0f) > 0.0f);
                v0a[j] = z ? 0.f : vd;
                i0a[j] = __fadd_rn(id, inp);
                zb0 |= (unsigned)z << j;
            }
            #pragma unroll
            for (int j = 0; j < 12; ++j) {
                const float inp = __fadd_rn(acc1[j], bias1);
                const float vd  = __fadd_rn(v0b[j], __fmul_rn(CM, __fsub_rn(i0b[j], v0b[j])));
                const float id  = __fmul_rn(i0b[j], CS);
                const int z = (__fsub_rn(vd, 1.0f) > 0.0f);
                v0b[j] = z ? 0.f : vd;
                i0b[j] = __fadd_rn(id, inp);
                zb1 |= (unsigned)z << j;
            }
            const unsigned int zp = zb0 | zb1;
            #pragma unroll
            for (int jj = 0; jj < 6; ++jj)
                p1[(c * 12 + pr) * 12 + chh * 6 + jj] = ((zp >> (2 * jj)) & 3u) ? 1.0f : 0.0f;
        }
        if (ts + 1 < TSTEPS) {
            xs[nxt][sr0 * 36 + sc0_] = xpre0;
            if (has2) xs[nxt][sr1 * 36 + sc1_] = xpre1;
        }
        __syncthreads();   // (B1) p1(ts) ready

        // ===== stage Q: conv2(ts) DENSE (global weights, reg double-buffer) + LIF2 =====
        if (l2) {
            float acc[8];
            #pragma unroll
            for (int xx = 0; xx < 8; ++xx) acc[xx] = 0.f;
            float4 ra, rb, rc;
            {
                const float4* pp = (const float4*)(p1 + y2 * 12);   // (ic=0,kr=0)
                ra = pp[0]; rb = pp[1]; rc = pp[2];
            }
            float wnxt[25];

            for (int ic = 0; ic < 20; ++ic) {
                if (ic + 1 < 20) {                   // next-ic weights early (global, 1 ic ahead)
                    #pragma unroll
                    for (int q = 0; q < 25; ++q) wnxt[q] = w2base[(ic + 1) * 25 + q];
                }
                #pragma unroll
                for (int kr = 0; kr < 5; ++kr) {
                    float4 na, nb, nc;
                    const bool last = (ic == 19) && (kr == 4);
                    if (!last) {                     // next row load
                        const int nic = (kr == 4) ? ic + 1 : ic;
                        const int nkr = (kr == 4) ? 0 : kr + 1;
                        const float4* pp = (const float4*)(p1 + (nic * 12 + y2 + nkr) * 12);
                        na = pp[0]; nb = pp[1]; nc = pp[2];
                    }
                    const float pv[12] = { ra.x,ra.y,ra.z,ra.w, rb.x,rb.y,rb.z,rb.w, rc.x,rc.y,rc.z,rc.w };
                    const float w0  = wcur[kr*5+0], w1_ = wcur[kr*5+1], w2w = wcur[kr*5+2];
                    const float w3_ = wcur[kr*5+3], w4_ = wcur[kr*5+4];
                    #pragma unroll
                    for (int xx = 0; xx < 8; ++xx) acc[xx] = __fmaf_rn(w0, pv[xx],     acc[xx]);
                    #pragma unroll
                    for (int xx = 0; xx < 8; ++xx) acc[xx] = __fmaf_rn(w1_, pv[xx + 1], acc[xx]);
                    #pragma unroll
                    for (int xx = 0; xx < 8; ++xx) acc[xx] = __fmaf_rn(w2w, pv[xx + 2], acc[xx]);
                    #pragma unroll
                    for (int xx = 0; xx < 8; ++xx) acc[xx] = __fmaf_rn(w3_, pv[xx + 3], acc[xx]);
                    #pragma unroll
                    for (int xx = 0; xx < 8; ++xx) acc[xx] = __fmaf_rn(w4_, pv[xx + 4], acc[xx]);
                    if (!last) { ra = na; rb = nb; rc = nc; }
                }
                if (ic + 1 < 20) {
                    #pragma unroll
                    for (int q = 0; q < 25; ++q) wcur[q] = wnxt[q];
                }
            }

            unsigned int pb = 0;                     // pooled bits for bm2
            const unsigned int bitbase = (unsigned)((oc2 & 1) * 16 + (y2 >> 1) * 4);
            #pragma unroll
            for (int xx = 0; xx < 8; ++xx) {
                const float inp = __fmul_rn(10.0f, __fadd_rn(acc[xx], bias2));
                const float vd  = __fadd_rn(vL2[xx], __fmul_rn(CM, __fsub_rn(iL2[xx], vL2[xx])));
                const float id  = __fmul_rn(iL2[xx], CS);
                const int z = (__fsub_rn(vd, 1.0f) > 0.0f);
                vL2[xx] = z ? 0.f : vd;
                iL2[xx] = __fadd_rn(id, inp);
                if (z) pb |= 1u << (bitbase + (xx >> 1));
            }
            if (pb) atomicOr(&bm2[oc2 >> 1], pb);
        }
        __syncthreads();   // (B2) bm2(ts) complete

        // ===== stage R: scan2(ts) on wave0 | scan3(ts-1) on wave1 =====
        if (tid < 64) {
            unsigned int bits = (tid < 25) ? bm2[tid] : 0u;
            if (tid < 25) bm2[tid] = 0u;             // consumed; next writer conv2(ts+1)
            int cnt = __popc(bits);
            int inc = cnt;
            #pragma unroll
            for (int d = 1; d < 32; d <<= 1) {
                int n = __shfl_up(inc, d);
                if (tid >= d) inc += n;
            }
            int off = inc - cnt;                     // exclusive prefix
            if (tid == 24) nn2s = inc;
            const int tot = __shfl(inc, 24);         // total, all lanes
            const int jstride = (int)fc_sj * 4;
            const int base = tid * 32;
            while (bits) {
                const int bb = __builtin_ctz(bits);
                bits &= bits - 1;
                list2i[off++] = (base + bb) * jstride;
            }
            if (tid >= 32) list2i[tot + (tid - 32)] = 0;   // 32-entry zero pad
        } else if (tid < 128 && ts > 0) {
            const int t3 = tid - 64;
            unsigned int bits = (t3 < 16) ? bm3[t3] : 0u;
            int cnt = __popc(bits);
            int inc = cnt;
            #pragma unroll
            for (int d = 1; d < 16; d <<= 1) {
                int n = __shfl_up(inc, d);
                if (t3 >= d) inc += n;
            }
            int off = inc - cnt;
            if (t3 == 15) nn3s = inc;
            while (bits) {
                const int bb = __builtin_ctz(bits);
                bits &= bits - 1;
                list3s[off++] = (unsigned short)(t3 * 32 + bb);
            }
        }
        __syncthreads();   // (B3) list2i(ts), list3s(ts-1) ready

        // ===== stage S: fc(ts)+LIF3 on tids 0-499 | out(ts-1) on tids 500-509 =====
        if (tid < 500) {
            const int nn2 = nn2s;
            float fca = 0.f;
            int k = 0;
            const int nb32 = nn2 >> 5;               // full 32-batches
            if (nb32 >= 1) {                          // ping-pong, guard-free
                float A[32], B[32];
                FC_LOAD32(A, 0);
                int j = 1;
                for (; j + 1 < nb32; j += 2) {
                    FC_LOAD32(B, j * 32);
                    FC_FMA32(fca, A);
                    FC_LOAD32(A, (j + 1) * 32);
                    FC_FMA32(fca, B);
                }
                if (j < nb32) {
                    FC_LOAD32(B, j * 32);
                    FC_FMA32(fca, A);
                    FC_FMA32(fca, B);
                } else {
                    FC_FMA32(fca, A);
                }
                k = nb32 * 32;
            }
            {                                         // tail <=31: unguarded loads (pad), guarded fma
                const int rem = nn2 - k;
                float T[31];
                #pragma unroll
                for (int q = 0; q < 31; ++q) {
                    const int o_ = RFL(list2i[k + q]);
                    T[q] = *(const float*)(fcb + (size_t)(unsigned)(o_ + coffE));
                }
                #pragma unroll
                for (int q = 0; q < 31; ++q)
                    if (q < rem) fca = __fmaf_rn(1.0f, T[q], fca);
            }
            const float inp = __fadd_rn(fca, bfc_r);
            const float vd  = __fadd_rn(vL3, __fmul_rn(CM, __fsub_rn(iL3, vL3)));
            const float id  = __fmul_rn(iL3, CS);
            const int z = (__fsub_rn(vd, 1.0f) > 0.0f);
            vL3 = z ? 0.f : vd;
            iL3 = __fadd_rn(id, inp);
            const unsigned long long m = __ballot(z); // full-word overwrite, no atomics
            if ((tid & 63) == 0) {
                bm3[(tid >> 5)]     = (unsigned int)m;
                bm3[(tid >> 5) + 1] = (unsigned int)(m >> 32);
            }
        } else if (tid < 510 && ts > 0) {
            const int otid = tid - 500;
            const float* wrow_ = woutL + otid * 500;
            const int nn3 = nn3s;
            float acc = 0.f;
            int k = 0;
            const int kfull = nn3 & ~7;
            if (kfull > 0) {                          // 8-wide, 2-deep pipeline (LDS)
                float a[8];
                #pragma unroll
                for (int q = 0; q < 8; ++q) a[q] = wrow_[list3s[q]];
                for (k = 8; k < kfull; k += 8) {
                    float bv[8];
                    #pragma unroll
                    for (int q = 0; q < 8; ++q) bv[q] = wrow_[list3s[k + q]];
                    #pragma unroll
                    for (int q = 0; q < 8; ++q) acc = __fmaf_rn(1.0f, a[q], acc);
                    #pragma unroll
                    for (int q = 0; q < 8; ++q) a[q] = bv[q];
                }
                #pragma unroll
                for (int q = 0; q < 8; ++q) acc = __fmaf_rn(1.0f, a[q], acc);
                k = kfull;
            }
            {
                const int rem3 = nn3 - k;
                float t[7];
                #pragma unroll
                for (int q = 0; q < 7; ++q) t[q] = (q < rem3) ? wrow_[list3s[k + q]] : 0.f;
                #pragma unroll
                for (int q = 0; q < 7; ++q) if (q < rem3) acc = __fmaf_rn(1.0f, t[q], acc);
            }
            const float vn = __fadd_rn(vO, __fmul_rn(CM, __fsub_rn(iO, vO)));
            iO = __fadd_rn(__fmul_rn(iO, CS), acc);
            vO = vn;
            out[((size_t)(ts - 1) * NB + b) * 10 + otid] = vn;
        }
        // no trailing barrier: list2i/list3s next rewritten in R(ts+1), which every
        // wave reaches only after crossing B1/B2(ts+1); P(ts+1) touches only xs/p1/x.
    }

    // ===== tail: scan3(63) + out(63) =====
    __syncthreads();
    if (tid < 64) {
        unsigned int bits = (tid < 16) ? bm3[tid] : 0u;
        int cnt = __popc(bits);
        int inc = cnt;
        #pragma unroll
        for (int d = 1; d < 16; d <<= 1) {
            int n = __shfl_up(inc, d);
            if (tid >= d) inc += n;
        }
        int off = inc - cnt;
        if (tid == 15) nn3s = inc;
        while (bits) {
            const int bb = __builtin_ctz(bits);
            bits &= bits - 1;
            list3s[off++] = (unsigned short)(tid * 32 + bb);
        }
    }
    __syncthreads();
    {
        const int otid = tid - 500;
        if (otid >= 0 && otid < 10) {
            const float* wrow_ = woutL + otid * 500;
            const int nn3 = nn3s;
            float acc = 0.f;
            int k = 0;
            const int kfull = nn3 & ~7;
            if (kfull > 0) {
                float a[8];
                #pragma unroll
                for (int q = 0; q < 8; ++q) a[q] = wrow_[list3s[q]];
                for (k = 8; k < kfull; k += 8) {
                    float bv[8];
                    #pragma unroll
                    for (int q = 0; q < 8; ++q) bv[q] = wrow_[list3s[k + q]];
                    #pragma unroll
                    for (int q = 0; q < 8; ++q) acc = __fmaf_rn(1.0f, a[q], acc);
                    #pragma unroll
                    for (int q = 0; q < 8; ++q) a[q] = bv[q];
                }
                #pragma unroll
                for (int q = 0; q < 8; ++q) acc = __fmaf_rn(1.0f, a[q], acc);
                k = kfull;
            }
            {
                const int rem3 = nn3 - k;
                float t[7];
                #pragma unroll
                for (int q = 0; q < 7; ++q) t[q] = (q < rem3) ? wrow_[list3s[k + q]] : 0.f;
                #pragma unroll
                for (int q = 0; q < 7; ++q) if (q < rem3) acc = __fmaf_rn(1.0f, t[q], acc);
            }
            const float vn = __fadd_rn(vO, __fmul_rn(CM, __fsub_rn(iO, vO)));
            iO = __fadd_rn(__fmul_rn(iO, CS), acc);
            vO = vn;
            out[((size_t)(TSTEPS - 1) * NB + b) * 10 + otid] = vn;
        }
    }
}

extern "C" void kernel_launch(void* const* d_in, const int* in_sizes, int n_in,
                              void* d_out, int out_size, void* d_ws, size_t ws_size,
                              hipStream_t stream)
{
    const float* x    = (const float*)d_in[0];
    const float* w1   = (const float*)d_in[1];
    const float* b1   = (const float*)d_in[2];
    const float* w2   = (const float*)d_in[3];
    const float* b2   = (const float*)d_in[4];
    const float* wfc  = (const float*)d_in[5];
    const float* bfc  = (const float*)d_in[6];
    const float* wout = (const float*)d_in[7];
    float* out = (float*)d_out;

    const float* fcptr = wfc;
    long sj = 1, so = 800;
    if (ws_size >= (size_t)500 * 800 * sizeof(float)) {
        float* wfcT = (float*)d_ws;
        transpose_wfc<<<(500 * 800 + 255) / 256, 256, 0, stream>>>(wfc, wfcT);
        fcptr = wfcT; sj = 500; so = 1;
    }

    snn_forward<<<NB, 512, 0, stream>>>(x, w1, b1, w2, b2, fcptr, sj, so, bfc, wout, out);
}